// Round 6
// baseline (948.743 us; speedup 1.0000x reference)
//
#include <hip/hip_runtime.h>
#include <stdint.h>

#define HCH 256     // H
#define INCH 128    // IN
#define WDIM 512    // WD
#define NRANK 10
#define SLOPE 0.01f
#define FB 64       // fused-kernel rows per block
#define AST 260     // LDS act row stride (floats): 260 mod 32 = 4 -> <=2-way banks

typedef __attribute__((ext_vector_type(8))) short bf16x8;
typedef __attribute__((ext_vector_type(4))) float f32x4;

__device__ __forceinline__ float b2f(ushort u) {
  union { uint32_t i; float f; } x; x.i = ((uint32_t)u) << 16; return x.f;
}
__device__ __forceinline__ ushort f2b(float f) {
  union { float f; uint32_t i; } x; x.f = f;
  uint32_t u = x.i;
  return (ushort)((u + 0x7fffu + ((u >> 16) & 1u)) >> 16);
}
__device__ __forceinline__ float leaky(float v) { return v >= 0.f ? v : SLOPE * v; }

// ---------------------------------------------------------------------------
__global__ void k_styles(const float* __restrict__ aw0, const float* __restrict__ ab0,
                         const float* __restrict__ aw1, const float* __restrict__ ab1,
                         const float* __restrict__ aw2, const float* __restrict__ ab2,
                         const float* __restrict__ w, float* __restrict__ styles) {
  int wid = blockIdx.x * 4 + (threadIdx.x >> 6);
  int lane = threadIdx.x & 63;
  int s = wid / 5120;
  int r = wid - s * 5120;
  const float* aw = (s == 0) ? aw0 : (s == 1) ? aw1 : aw2;
  const float* ab = (s == 0) ? ab0 : (s == 1) ? ab1 : ab2;
  const float4* ap = (const float4*)(aw + (size_t)r * WDIM + lane * 8);
  const float4* wp = (const float4*)(w + lane * 8);
  float4 a0 = ap[0], a1 = ap[1], w0 = wp[0], w1 = wp[1];
  float sum = a0.x * w0.x + a0.y * w0.y + a0.z * w0.z + a0.w * w0.w +
              a1.x * w1.x + a1.y * w1.y + a1.z * w1.z + a1.w * w1.w;
#pragma unroll
  for (int off = 32; off > 0; off >>= 1) sum += __shfl_down(sum, off);
  if (lane == 0) styles[wid] = sum + ab[r];
}

// ---------------------------------------------------------------------------
// Modulated + row-normalized weights, split into bf16 hi/lo planes.
__global__ void k_weights(const float* __restrict__ styles,
                          const float* __restrict__ wt0, const float* __restrict__ bs0,
                          const float* __restrict__ wt1, const float* __restrict__ bs1,
                          const float* __restrict__ wt2, const float* __restrict__ bs2,
                          ushort* __restrict__ W0H, ushort* __restrict__ W0L,
                          ushort* __restrict__ W1H, ushort* __restrict__ W1L,
                          ushort* __restrict__ W2H, ushort* __restrict__ W2L,
                          float* __restrict__ biasf) {
  int s = blockIdx.x >> 8;
  int o = blockIdx.x & 255;
  int k = threadIdx.x;
  const float* st = styles + s * 5120;
  const float* wt = (s == 0) ? wt0 : (s == 1) ? wt1 : wt2;
  const float* bs = (s == 0) ? bs0 : (s == 1) ? bs1 : bs2;
  ushort* WH = (s == 0) ? W0H : (s == 1) ? W1H : W2H;
  ushort* WL = (s == 0) ? W0L : (s == 1) ? W1L : W2L;
  float mod = 0.f;
#pragma unroll
  for (int r = 0; r < NRANK; r++)
    mod += st[o * NRANK + r] * st[HCH * NRANK + r * HCH + k];
  mod *= 0.31622776601683794f;  // 1/sqrt(RANK)
  float wv = wt[o * HCH + k] * (mod + 1.0f);
  __shared__ float red[HCH];
  red[k] = wv * wv;
  __syncthreads();
  for (int t = 128; t > 0; t >>= 1) {
    if (k < t) red[k] += red[k + t];
    __syncthreads();
  }
  float inv = 1.0f / (sqrtf(red[0]) + 1e-8f);
  float wn = wv * inv;
  ushort h = f2b(wn);
  WH[o * HCH + k] = h;
  WL[o * HCH + k] = f2b(wn - b2f(h));
  if (k == 0) biasf[s * HCH + o] = bs[o];
}

// ---------------------------------------------------------------------------
// M1 = I+cat1_w -> hi/lo;  K2 = (I+cat2_w)@nm_w (256x128) -> hi/lo;
// b23 = cat1_b + cat2_b + (I+cat2_w)@nm_b
__global__ void k_prep(const float* __restrict__ cat1_w, const float* __restrict__ cat1_b,
                       const float* __restrict__ cat2_w, const float* __restrict__ cat2_b,
                       const float* __restrict__ nm_w, const float* __restrict__ nm_b,
                       ushort* __restrict__ M1H, ushort* __restrict__ M1L,
                       ushort* __restrict__ K2H, ushort* __restrict__ K2L,
                       float* __restrict__ b23) {
  int o = blockIdx.x;
  int t = threadIdx.x;
  for (int k = t; k < HCH; k += 128) {
    float v = cat1_w[o * HCH + k] + ((k == o) ? 1.f : 0.f);
    ushort h = f2b(v);
    M1H[o * HCH + k] = h;
    M1L[o * HCH + k] = f2b(v - b2f(h));
  }
  float acc = 0.f;
  for (int k = 0; k < HCH; k++) {
    float m2 = cat2_w[o * HCH + k] + ((k == o) ? 1.f : 0.f);
    acc += m2 * nm_w[k * INCH + t];
  }
  ushort h2 = f2b(acc);
  K2H[o * INCH + t] = h2;
  K2L[o * INCH + t] = f2b(acc - b2f(h2));
  if (t == 0) {
    float bb = cat1_b[o] + cat2_b[o];
    for (int k = 0; k < HCH; k++)
      bb += (cat2_w[o * HCH + k] + ((k == o) ? 1.f : 0.f)) * nm_b[k];
    b23[o] = bb;
  }
}

// ---------------------------------------------------------------------------
// CSR build
__global__ void k_zero(int* __restrict__ p, int n) {
  int i = blockIdx.x * blockDim.x + threadIdx.x;
  if (i < n) p[i] = 0;
}
__global__ void k_hist(const int* __restrict__ ei, int* __restrict__ cnt, int E) {
  int e = blockIdx.x * blockDim.x + threadIdx.x;
  if (e < E) atomicAdd(&cnt[ei[E + e]], 1);
}
__global__ void k_bsum(const int* __restrict__ cnt, int* __restrict__ bsum, int N) {
  __shared__ int red[256];
  int t = threadIdx.x;
  int i = blockIdx.x * 256 + t;
  red[t] = (i < N) ? cnt[i] : 0;
  __syncthreads();
  for (int d = 128; d > 0; d >>= 1) {
    if (t < d) red[t] += red[t + d];
    __syncthreads();
  }
  if (t == 0) bsum[blockIdx.x] = red[0];
}
__global__ void k_scanb(int* __restrict__ bsum, int* __restrict__ offsets, int NB,
                        int N, int E) {
  if (threadIdx.x == 0) {
    int run = 0;
    for (int b = 0; b < NB; b++) { int v = bsum[b]; bsum[b] = run; run += v; }
    offsets[N] = E;
  }
}
__global__ void k_scanseg(int* __restrict__ cnt, const int* __restrict__ bsum,
                          int* __restrict__ offsets, int N) {
  __shared__ int s[256];
  int t = threadIdx.x;
  int i = blockIdx.x * 256 + t;
  int v = (i < N) ? cnt[i] : 0;
  s[t] = v;
  __syncthreads();
  for (int d = 1; d < 256; d <<= 1) {
    int tv = (t >= d) ? s[t - d] : 0;
    __syncthreads();
    s[t] += tv;
    __syncthreads();
  }
  if (i < N) {
    offsets[i] = bsum[blockIdx.x] + s[t] - v;
    cnt[i] = 0;
  }
}
__global__ void k_place(const int* __restrict__ ei, const int* __restrict__ offsets,
                        int* __restrict__ cur, int* __restrict__ csr, int E) {
  int e = blockIdx.x * blockDim.x + threadIdx.x;
  if (e >= E) return;
  int dst = ei[E + e];
  int pos = atomicAdd(&cur[dst], 1);
  csr[offsets[dst] + pos] = ei[e];
}

// ---------------------------------------------------------------------------
// Pull aggregation: one wave per node; lane owns 4 channels.
__global__ void k_pull(const int* __restrict__ csr, const int* __restrict__ offsets,
                       const float* __restrict__ nw, const float* __restrict__ eb,
                       float* __restrict__ agg, int r0, int Mc) {
  int wid = blockIdx.x * 4 + (threadIdx.x >> 6);
  if (wid >= Mc) return;
  int lane = threadIdx.x & 63;
  int node = r0 + wid;
  int s0 = offsets[node], s1 = offsets[node + 1];
  float4 acc = *(const float4*)(eb + lane * 4);
  float4 acc2 = make_float4(0.f, 0.f, 0.f, 0.f);
  int j = s0;
  for (; j + 1 < s1; j += 2) {
    int sa = csr[j], sb = csr[j + 1];
    float4 va = *(const float4*)(nw + (size_t)sa * HCH + lane * 4);
    float4 vb = *(const float4*)(nw + (size_t)sb * HCH + lane * 4);
    acc.x += va.x; acc.y += va.y; acc.z += va.z; acc.w += va.w;
    acc2.x += vb.x; acc2.y += vb.y; acc2.z += vb.z; acc2.w += vb.w;
  }
  if (j < s1) {
    int sa = csr[j];
    float4 va = *(const float4*)(nw + (size_t)sa * HCH + lane * 4);
    acc.x += va.x; acc.y += va.y; acc.z += va.z; acc.w += va.w;
  }
  acc.x += acc2.x; acc.y += acc2.y; acc.z += acc2.z; acc.w += acc2.w;
  *(float4*)(agg + (size_t)wid * HCH + lane * 4) = acc;
}

// ---------------------------------------------------------------------------
// Fused 4-layer synth chain on split-bf16 MFMA. One block = 64 rows.
// act (fp32) lives in LDS across layers; weights pre-split into bf16 hi/lo.

__device__ __forceinline__ void mk_frag(const float* ap, bf16x8& hi, bf16x8& lo) {
  float4 a0 = *(const float4*)ap;
  float4 a1 = *(const float4*)(ap + 4);
  float av[8] = {a0.x, a0.y, a0.z, a0.w, a1.x, a1.y, a1.z, a1.w};
#pragma unroll
  for (int j = 0; j < 8; j++) {
    ushort h = f2b(av[j]);
    hi[j] = (short)h;
    lo[j] = (short)f2b(av[j] - b2f(h));
  }
}

__device__ __forceinline__ void layer_lds(const float* act, int mrow,
    const ushort* __restrict__ WH, const ushort* __restrict__ WL, int wstr, int nk,
    f32x4* acc, int l16, int quad) {
  for (int k0 = 0; k0 < nk; k0++) {
    bf16x8 ah, al;
    mk_frag(act + (mrow + l16) * AST + k0 * 32 + quad * 8, ah, al);
    const ushort* bh0 = WH + (size_t)l16 * wstr + k0 * 32 + quad * 8;
    const ushort* bl0 = WL + (size_t)l16 * wstr + k0 * 32 + quad * 8;
#pragma unroll
    for (int nt = 0; nt < 16; nt++) {
      bf16x8 bh = *(const bf16x8*)(bh0 + (size_t)nt * 16 * wstr);
      bf16x8 bl = *(const bf16x8*)(bl0 + (size_t)nt * 16 * wstr);
      acc[nt] = __builtin_amdgcn_mfma_f32_16x16x32_bf16(ah, bh, acc[nt], 0, 0, 0);
      acc[nt] = __builtin_amdgcn_mfma_f32_16x16x32_bf16(ah, bl, acc[nt], 0, 0, 0);
      acc[nt] = __builtin_amdgcn_mfma_f32_16x16x32_bf16(al, bh, acc[nt], 0, 0, 0);
    }
  }
}

__device__ __forceinline__ void layer_x(const float* __restrict__ x, size_t grow,
    const ushort* __restrict__ WH, const ushort* __restrict__ WL,
    f32x4* acc, int l16, int quad) {
  const float* xr = x + grow * INCH;
  for (int k0 = 0; k0 < 4; k0++) {
    bf16x8 ah, al;
    mk_frag(xr + k0 * 32 + quad * 8, ah, al);
    const ushort* bh0 = WH + (size_t)l16 * INCH + k0 * 32 + quad * 8;
    const ushort* bl0 = WL + (size_t)l16 * INCH + k0 * 32 + quad * 8;
#pragma unroll
    for (int nt = 0; nt < 16; nt++) {
      bf16x8 bh = *(const bf16x8*)(bh0 + (size_t)nt * 16 * INCH);
      bf16x8 bl = *(const bf16x8*)(bl0 + (size_t)nt * 16 * INCH);
      acc[nt] = __builtin_amdgcn_mfma_f32_16x16x32_bf16(ah, bh, acc[nt], 0, 0, 0);
      acc[nt] = __builtin_amdgcn_mfma_f32_16x16x32_bf16(ah, bl, acc[nt], 0, 0, 0);
      acc[nt] = __builtin_amdgcn_mfma_f32_16x16x32_bf16(al, bh, acc[nt], 0, 0, 0);
    }
  }
}

__device__ __forceinline__ void epi_lds(float* act, int mrow,
    const float* __restrict__ bias, f32x4* acc, int l16, int quad) {
  __syncthreads();  // all reads of act done (layer fully in acc)
#pragma unroll
  for (int nt = 0; nt < 16; nt++) {
    float bv = bias[nt * 16 + l16];
#pragma unroll
    for (int r = 0; r < 4; r++)
      act[(mrow + quad * 4 + r) * AST + nt * 16 + l16] = leaky(acc[nt][r] + bv);
  }
  __syncthreads();
}

__global__ __launch_bounds__(256, 2) void k_fused(
    const float* __restrict__ agg, const float* __restrict__ x, size_t xrow0,
    const ushort* __restrict__ WleH, const ushort* __restrict__ WleL,
    const ushort* __restrict__ M1H, const ushort* __restrict__ M1L,
    const ushort* __restrict__ K2H, const ushort* __restrict__ K2L,
    const ushort* __restrict__ Wf1H, const ushort* __restrict__ Wf1L,
    const ushort* __restrict__ Wf2H, const ushort* __restrict__ Wf2L,
    const float* __restrict__ biasf, const float* __restrict__ b23,
    float* __restrict__ out, size_t outrow0, int M) {
  __shared__ float act[FB * AST];
  int tid = threadIdx.x;
  int lane = tid & 63;
  int wv = tid >> 6;
  int quad = lane >> 4, l16 = lane & 15;
  int row0 = blockIdx.x * FB;
  int mrow = wv * 16;

  // stage agg block -> LDS (coalesced float4)
#pragma unroll
  for (int i = 0; i < 16; i++) {
    int idx = i * 256 + tid;
    int r = idx >> 6, c4 = idx & 63;
    int gr = row0 + r;
    if (gr >= M) gr = M - 1;
    *(float4*)(act + r * AST + c4 * 4) =
        *(const float4*)(agg + (size_t)gr * HCH + c4 * 4);
  }
  __syncthreads();

  f32x4 acc[16];
  // ---- L1: leaky(agg @ Wle^T + b_le)
#pragma unroll
  for (int nt = 0; nt < 16; nt++) acc[nt] = (f32x4)(0.f);
  layer_lds(act, mrow, WleH, WleL, HCH, 8, acc, l16, quad);
  epi_lds(act, mrow, biasf, acc, l16, quad);
  // ---- L2: leaky(h1 @ M1^T + x @ K2^T + b23)
#pragma unroll
  for (int nt = 0; nt < 16; nt++) acc[nt] = (f32x4)(0.f);
  layer_lds(act, mrow, M1H, M1L, HCH, 8, acc, l16, quad);
  {
    int gr = row0 + mrow + l16;
    if (gr >= M) gr = M - 1;
    layer_x(x, xrow0 + (size_t)gr, K2H, K2L, acc, l16, quad);
  }
  epi_lds(act, mrow, b23, acc, l16, quad);
  // ---- L3: leaky(h2 @ Wf1^T + b_f1)
#pragma unroll
  for (int nt = 0; nt < 16; nt++) acc[nt] = (f32x4)(0.f);
  layer_lds(act, mrow, Wf1H, Wf1L, HCH, 8, acc, l16, quad);
  epi_lds(act, mrow, biasf + HCH, acc, l16, quad);
  // ---- L4: leaky(h3 @ Wf2^T + b_f2) -> global
#pragma unroll
  for (int nt = 0; nt < 16; nt++) acc[nt] = (f32x4)(0.f);
  layer_lds(act, mrow, Wf2H, Wf2L, HCH, 8, acc, l16, quad);
#pragma unroll
  for (int nt = 0; nt < 16; nt++) {
    float bv = biasf[2 * HCH + nt * 16 + l16];
#pragma unroll
    for (int r = 0; r < 4; r++) {
      int gm = row0 + mrow + quad * 4 + r;
      if (gm < M)
        out[(outrow0 + (size_t)gm) * HCH + nt * 16 + l16] = leaky(acc[nt][r] + bv);
    }
  }
}

// ---------------------------------------------------------------------------
extern "C" void kernel_launch(void* const* d_in, const int* in_sizes, int n_in,
                              void* d_out, int out_size, void* d_ws, size_t ws_size,
                              hipStream_t stream) {
  const float* x      = (const float*)d_in[0];
  const int*   ei     = (const int*)d_in[1];
  const float* w      = (const float*)d_in[2];
  const float* nw     = (const float*)d_in[3];
  const float* eb     = (const float*)d_in[4];
  const float* le_aw  = (const float*)d_in[5];
  const float* le_ab  = (const float*)d_in[6];
  const float* le_w   = (const float*)d_in[7];
  const float* le_b   = (const float*)d_in[8];
  const float* cat1_w = (const float*)d_in[10];
  const float* cat1_b = (const float*)d_in[11];
  const float* cat2_w = (const float*)d_in[12];
  const float* cat2_b = (const float*)d_in[13];
  const float* nm_w   = (const float*)d_in[14];
  const float* nm_b   = (const float*)d_in[15];
  const float* f1_aw  = (const float*)d_in[16];
  const float* f1_ab  = (const float*)d_in[17];
  const float* f1_w   = (const float*)d_in[18];
  const float* f1_b   = (const float*)d_in[19];
  const float* f2_aw  = (const float*)d_in[21];
  const float* f2_ab  = (const float*)d_in[22];
  const float* f2_w   = (const float*)d_in[23];
  const float* f2_b   = (const float*)d_in[24];

  const int N = in_sizes[3] / HCH;  // 50000
  const int E = in_sizes[1] / 2;    // 800000
  const int NB = (N + 255) / 256;

  uint8_t* ws = (uint8_t*)d_ws;
  float*  styles = (float*)(ws + 0);          // 61440 B
  float*  biasf  = (float*)(ws + 65536);      // 3072 B
  float*  b23    = (float*)(ws + 69632);      // 1024 B
  ushort* WleH   = (ushort*)(ws + 131072);    // 256x256 bf16 = 131072 B each
  ushort* WleL   = (ushort*)(ws + 262144);
  ushort* Wf1H   = (ushort*)(ws + 393216);
  ushort* Wf1L   = (ushort*)(ws + 524288);
  ushort* Wf2H   = (ushort*)(ws + 655360);
  ushort* Wf2L   = (ushort*)(ws + 786432);
  ushort* M1H    = (ushort*)(ws + 917504);
  ushort* M1L    = (ushort*)(ws + 1048576);
  ushort* K2H    = (ushort*)(ws + 1179648);   // 256x128 bf16 = 65536 B
  ushort* K2L    = (ushort*)(ws + 1245184);
  int*    cnt    = (int*)(ws + 1310720);      // N ints (<=262144 B)
  int*    bsum   = (int*)(ws + 1572864);      // NB ints
  int*    offs   = (int*)(ws + 1576960);      // N+1 ints
  int*    csr    = (int*)(ws + 1839104);      // E ints
  size_t bigoff  = 1839104 + (size_t)E * 4;
  bigoff = (bigoff + 1023) & ~(size_t)1023;

  // adaptive chunk for agg (only large buffer): cn rows of 1 KB
  long long availl = (long long)ws_size - (long long)bigoff;
  long long cnl = (availl > 0) ? availl / (HCH * (long long)sizeof(float)) : 0;
  int cn = (cnl > N) ? N : (int)cnl;
  if (cn < 4096) cn = 4096;
  int nchunks = (N + cn - 1) / cn;
  float* agg = (float*)(ws + bigoff);

  k_styles<<<3840, 256, 0, stream>>>(le_aw, le_ab, f1_aw, f1_ab, f2_aw, f2_ab, w, styles);
  k_weights<<<768, 256, 0, stream>>>(styles, le_w, le_b, f1_w, f1_b, f2_w, f2_b,
                                     WleH, WleL, Wf1H, Wf1L, Wf2H, Wf2L, biasf);
  k_prep<<<256, 128, 0, stream>>>(cat1_w, cat1_b, cat2_w, cat2_b, nm_w, nm_b,
                                  M1H, M1L, K2H, K2L, b23);

  int eb256 = (E + 255) / 256;
  k_zero<<<NB, 256, 0, stream>>>(cnt, N);
  k_hist<<<eb256, 256, 0, stream>>>(ei, cnt, E);
  k_bsum<<<NB, 256, 0, stream>>>(cnt, bsum, N);
  k_scanb<<<1, 64, 0, stream>>>(bsum, offs, NB, N, E);
  k_scanseg<<<NB, 256, 0, stream>>>(cnt, bsum, offs, N);
  k_place<<<eb256, 256, 0, stream>>>(ei, offs, cnt, csr, E);

  for (int c = 0; c < nchunks; c++) {
    int r0 = c * cn;
    int Mc = N - r0;
    if (Mc > cn) Mc = cn;
    if (Mc <= 0) continue;
    k_pull<<<(Mc + 3) / 4, 256, 0, stream>>>(csr, offs, nw, eb, agg, r0, Mc);
    k_fused<<<(Mc + FB - 1) / FB, 256, 0, stream>>>(
        agg, x, (size_t)r0, WleH, WleL, M1H, M1L, K2H, K2L,
        Wf1H, Wf1L, Wf2H, Wf2L, biasf, b23, (float*)d_out, (size_t)r0, Mc);
  }
}